// Round 1
// baseline (1556.648 us; speedup 1.0000x reference)
//
#include <hip/hip_runtime.h>

#define HID 128

// ---------------- CSR build ----------------

__global__ __launch_bounds__(256) void count_dst(const int* __restrict__ ei,
                                                 int* __restrict__ cnt, int E) {
  int e = blockIdx.x * 256 + threadIdx.x;
  if (e < E) atomicAdd(&cnt[ei[E + e]], 1);
}

__global__ __launch_bounds__(256) void compute_dinv(const int* __restrict__ cnt,
                                                    float* __restrict__ dinv, int N) {
  int i = blockIdx.x * 256 + threadIdx.x;
  if (i < N) dinv[i] = rsqrtf((float)(cnt[i] + 1));
}

__global__ __launch_bounds__(256) void scan_block(const int* __restrict__ cnt,
                                                  int* __restrict__ rowptr,
                                                  int* __restrict__ bsum, int N) {
  __shared__ int s[256];
  int i = blockIdx.x * 256 + threadIdx.x;
  int v = (i < N) ? cnt[i] : 0;
  s[threadIdx.x] = v;
  __syncthreads();
#pragma unroll
  for (int off = 1; off < 256; off <<= 1) {
    int t = (threadIdx.x >= off) ? s[threadIdx.x - off] : 0;
    __syncthreads();
    s[threadIdx.x] += t;
    __syncthreads();
  }
  if (i < N) rowptr[i] = s[threadIdx.x] - v;  // exclusive within block
  if (threadIdx.x == 255) bsum[blockIdx.x] = s[255];
}

__global__ __launch_bounds__(512) void scan_bsum_k(int* __restrict__ bsum, int NB) {
  __shared__ int s[512];
  int v = (threadIdx.x < NB) ? bsum[threadIdx.x] : 0;
  s[threadIdx.x] = v;
  __syncthreads();
#pragma unroll
  for (int off = 1; off < 512; off <<= 1) {
    int t = (threadIdx.x >= off) ? s[threadIdx.x - off] : 0;
    __syncthreads();
    s[threadIdx.x] += t;
    __syncthreads();
  }
  if (threadIdx.x < NB) bsum[threadIdx.x] = s[threadIdx.x] - v;  // exclusive block offsets
}

__global__ __launch_bounds__(256) void add_off(int* __restrict__ rowptr,
                                               const int* __restrict__ bsum, int N, int E) {
  int i = blockIdx.x * 256 + threadIdx.x;
  if (i < N) rowptr[i] += bsum[blockIdx.x];
  if (i == 0) rowptr[N] = E;
}

__global__ __launch_bounds__(256) void fill_csr(const int* __restrict__ ei,
                                                const int* __restrict__ rowptr,
                                                int* __restrict__ cursor,
                                                int* __restrict__ colarr, int E) {
  int e = blockIdx.x * 256 + threadIdx.x;
  if (e < E) {
    int d = ei[E + e];
    int pos = rowptr[d] + atomicAdd(&cursor[d], 1);
    colarr[pos] = ei[e];  // src
  }
}

// ---------------- dense GEMM: out[N][128] = A[N][K] @ W[128][K]^T ----------------
// epilogue: optional per-row scale, optional bias, optional relu

__global__ __launch_bounds__(256) void gemm_nk(const float* __restrict__ A,
                                               const float* __restrict__ W,
                                               const float* __restrict__ bias,
                                               const float* __restrict__ rowscale,
                                               float* __restrict__ out,
                                               int N, int K, int do_relu) {
  __shared__ float As[64][36];   // BM=64, BK=32, pad to 36 (16B-aligned rows)
  __shared__ float Bs[32][132];  // Bs[k][c], pad 132 to break write conflicts

  const int tid = threadIdx.x;
  const int row0 = blockIdx.x * 64;
  const int tc = tid & 31;  // col quad: cols tc*4 .. tc*4+3
  const int tr = tid >> 5;  // 0..7 : rows tr*8 .. tr*8+7

  float acc[8][4] = {};

  for (int k0 = 0; k0 < K; k0 += 32) {
    // A tile: 64 x 32 = 512 float4, 2 per thread
#pragma unroll
    for (int i = 0; i < 2; ++i) {
      int idx = tid * 2 + i;  // 0..511
      int r = idx >> 3;
      int kq = idx & 7;
      float4 v = make_float4(0.f, 0.f, 0.f, 0.f);
      int gr = row0 + r;
      if (gr < N) v = *(const float4*)(A + (size_t)gr * K + k0 + kq * 4);
      *(float4*)&As[r][kq * 4] = v;
    }
    // B tile: W[c][k0+..] -> Bs[k][c]; 128 x 32 = 1024 float4, 4 per thread
#pragma unroll
    for (int i = 0; i < 4; ++i) {
      int idx = tid + i * 256;  // 0..1023
      int c = idx >> 3;
      int kq = idx & 7;
      float4 v = *(const float4*)(W + (size_t)c * K + k0 + kq * 4);
      Bs[kq * 4 + 0][c] = v.x;
      Bs[kq * 4 + 1][c] = v.y;
      Bs[kq * 4 + 2][c] = v.z;
      Bs[kq * 4 + 3][c] = v.w;
    }
    __syncthreads();

#pragma unroll
    for (int kk = 0; kk < 32; kk += 4) {
      float4 b0 = *(const float4*)&Bs[kk + 0][tc * 4];
      float4 b1 = *(const float4*)&Bs[kk + 1][tc * 4];
      float4 b2 = *(const float4*)&Bs[kk + 2][tc * 4];
      float4 b3 = *(const float4*)&Bs[kk + 3][tc * 4];
#pragma unroll
      for (int r = 0; r < 8; ++r) {
        float4 a = *(const float4*)&As[tr * 8 + r][kk];
        acc[r][0] += a.x * b0.x + a.y * b1.x + a.z * b2.x + a.w * b3.x;
        acc[r][1] += a.x * b0.y + a.y * b1.y + a.z * b2.y + a.w * b3.y;
        acc[r][2] += a.x * b0.z + a.y * b1.z + a.z * b2.z + a.w * b3.z;
        acc[r][3] += a.x * b0.w + a.y * b1.w + a.z * b2.w + a.w * b3.w;
      }
    }
    __syncthreads();
  }

#pragma unroll
  for (int r = 0; r < 8; ++r) {
    int gr = row0 + tr * 8 + r;
    if (gr >= N) break;
    float s = rowscale ? rowscale[gr] : 1.f;
    float4 v;
    v.x = acc[r][0] * s;
    v.y = acc[r][1] * s;
    v.z = acc[r][2] * s;
    v.w = acc[r][3] * s;
    if (bias) {
      v.x += bias[tc * 4 + 0];
      v.y += bias[tc * 4 + 1];
      v.z += bias[tc * 4 + 2];
      v.w += bias[tc * 4 + 3];
    }
    if (do_relu) {
      v.x = fmaxf(v.x, 0.f);
      v.y = fmaxf(v.y, 0.f);
      v.z = fmaxf(v.z, 0.f);
      v.w = fmaxf(v.w, 0.f);
    }
    *(float4*)(out + (size_t)gr * HID + tc * 4) = v;
  }
}

// ---------------- sparse aggregation ----------------
// out[i] = relu(dinv[i] * (g[i] + sum_{e in in(i)} g[src_e]) + bias)

__global__ __launch_bounds__(256) void agg(const float* __restrict__ g,
                                           const int* __restrict__ rowptr,
                                           const int* __restrict__ colarr,
                                           const float* __restrict__ dinv,
                                           const float* __restrict__ bias,
                                           float* __restrict__ out, int N) {
  int node = blockIdx.x * 2 + (threadIdx.x >> 7);
  int f = threadIdx.x & 127;
  if (node >= N) return;
  float acc0 = g[(size_t)node * HID + f];
  float acc1 = 0.f;
  int e = rowptr[node];
  int end = rowptr[node + 1];
  for (; e + 1 < end; e += 2) {
    int c0 = colarr[e];
    int c1 = colarr[e + 1];
    float v0 = g[(size_t)c0 * HID + f];
    float v1 = g[(size_t)c1 * HID + f];
    acc0 += v0;
    acc1 += v1;
  }
  if (e < end) acc0 += g[(size_t)colarr[e] * HID + f];
  float v = dinv[node] * (acc0 + acc1) + bias[f];
  out[(size_t)node * HID + f] = fmaxf(v, 0.f);
}

// ---------------- final GEMM: logits[N][40] = h[N][128] @ Wl[40][128]^T + bl ----------------

__global__ __launch_bounds__(256) void gemm40(const float* __restrict__ h,
                                              const float* __restrict__ Wl,
                                              const float* __restrict__ bl,
                                              float* __restrict__ out, int N) {
  __shared__ float hs[64][129];
  __shared__ float ws[128][40];
  const int tid = threadIdx.x;
  const int row0 = blockIdx.x * 64;

  for (int idx = tid; idx < 40 * 128; idx += 256) {
    int c = idx >> 7;
    int k = idx & 127;
    ws[k][c] = Wl[idx];  // Wl[c][k]
  }
#pragma unroll
  for (int i = 0; i < 8; ++i) {
    int idx = tid + i * 256;  // float4 index 0..2047
    int r = idx >> 5;
    int kq = idx & 31;
    float4 v = make_float4(0.f, 0.f, 0.f, 0.f);
    int gr = row0 + r;
    if (gr < N) v = *(const float4*)(h + (size_t)gr * HID + kq * 4);
    hs[r][kq * 4 + 0] = v.x;
    hs[r][kq * 4 + 1] = v.y;
    hs[r][kq * 4 + 2] = v.z;
    hs[r][kq * 4 + 3] = v.w;
  }
  __syncthreads();

  const int cg = tid & 7;   // 8 col groups of 5 cols
  const int rw = tid >> 3;  // 0..31; rows rw and rw+32
  float acc[2][5] = {};
#pragma unroll 4
  for (int k = 0; k < 128; ++k) {
    float a0 = hs[rw][k];
    float a1 = hs[rw + 32][k];
#pragma unroll
    for (int j = 0; j < 5; ++j) {
      float w = ws[k][cg * 5 + j];
      acc[0][j] += a0 * w;
      acc[1][j] += a1 * w;
    }
  }
#pragma unroll
  for (int half = 0; half < 2; ++half) {
    int gr = row0 + rw + half * 32;
    if (gr < N) {
#pragma unroll
      for (int j = 0; j < 5; ++j) {
        int c = cg * 5 + j;
        out[(size_t)gr * 40 + c] = acc[half][j] + bl[c];
      }
    }
  }
}

// ---------------- launch ----------------

extern "C" void kernel_launch(void* const* d_in, const int* in_sizes, int n_in,
                              void* d_out, int out_size, void* d_ws, size_t ws_size,
                              hipStream_t stream) {
  const float* x = (const float*)d_in[0];
  const int* ei = (const int*)d_in[1];
  const float* W0 = (const float*)d_in[2];
  const float* b0 = (const float*)d_in[3];
  const float* Wc = (const float*)d_in[4];
  const float* bc = (const float*)d_in[5];
  const float* Wl = (const float*)d_in[6];
  const float* bl = (const float*)d_in[7];
  float* out = (float*)d_out;

  const int N = in_sizes[0] / 512;
  const int E = in_sizes[1] / 2;

  char* ws = (char*)d_ws;
  size_t off = 0;
  auto alloc = [&](size_t bytes) -> char* {
    char* p = ws + off;
    off += (bytes + 511) & ~(size_t)511;
    return p;
  };
  float* dinv = (float*)alloc((size_t)N * 4);
  int* cnt = (int*)alloc((size_t)N * 4);
  int* rowptr = (int*)alloc((size_t)(N + 1) * 4);
  int* bsum = (int*)alloc(512 * 4);
  int* colarr = (int*)alloc((size_t)E * 4);
  float* hA = (float*)alloc((size_t)N * HID * 4);
  float* hB = (float*)alloc((size_t)N * HID * 4);
  float* hG = (float*)alloc((size_t)N * HID * 4);

  const int nb_n = (N + 255) / 256;
  const int nb_e = (E + 255) / 256;
  const int nb_g = (N + 63) / 64;

  hipMemsetAsync(cnt, 0, (size_t)N * 4, stream);
  count_dst<<<nb_e, 256, 0, stream>>>(ei, cnt, E);
  compute_dinv<<<nb_n, 256, 0, stream>>>(cnt, dinv, N);
  scan_block<<<nb_n, 256, 0, stream>>>(cnt, rowptr, bsum, N);
  scan_bsum_k<<<1, 512, 0, stream>>>(bsum, nb_n);
  add_off<<<nb_n, 256, 0, stream>>>(rowptr, bsum, N, E);
  hipMemsetAsync(cnt, 0, (size_t)N * 4, stream);
  fill_csr<<<nb_e, 256, 0, stream>>>(ei, rowptr, cnt, colarr, E);

  // input layer: hA = relu(x @ W0^T + b0)
  gemm_nk<<<nb_g, 256, 0, stream>>>(x, W0, b0, nullptr, hA, N, 512, 1);

  float* bufs[2] = {hA, hB};
  int cur = 0;
  for (int l = 0; l < 3; ++l) {
    // g = dinv * (h @ Wc[l]^T)
    gemm_nk<<<nb_g, 256, 0, stream>>>(bufs[cur], Wc + (size_t)l * HID * HID, nullptr, dinv,
                                      hG, N, HID, 0);
    // h' = relu(dinv * (g[i] + sum g[src]) + bc[l])
    agg<<<(N + 1) / 2, 256, 0, stream>>>(hG, rowptr, colarr, dinv, bc + (size_t)l * HID,
                                         bufs[1 - cur], N);
    cur = 1 - cur;
  }

  gemm40<<<nb_g, 256, 0, stream>>>(bufs[cur], Wl, bl, out, N);
}

// Round 2
// 580.813 us; speedup vs baseline: 2.6801x; 2.6801x over previous
//
#include <hip/hip_runtime.h>

#define HID 128

typedef _Float16 half8 __attribute__((ext_vector_type(8)));
typedef _Float16 half2v __attribute__((ext_vector_type(2)));
typedef float f32x4 __attribute__((ext_vector_type(4)));

// ---------------- CSR build ----------------

__global__ __launch_bounds__(256) void count_dst(const int* __restrict__ ei,
                                                 int* __restrict__ cnt, int E) {
  int e = blockIdx.x * 256 + threadIdx.x;
  if (e < E) atomicAdd(&cnt[ei[E + e]], 1);
}

__global__ __launch_bounds__(256) void compute_dinv(const int* __restrict__ cnt,
                                                    float* __restrict__ dinv, int N) {
  int i = blockIdx.x * 256 + threadIdx.x;
  if (i < N) dinv[i] = rsqrtf((float)(cnt[i] + 1));
}

__global__ __launch_bounds__(256) void scan_block(const int* __restrict__ cnt,
                                                  int* __restrict__ rowptr,
                                                  int* __restrict__ bsum, int N) {
  __shared__ int s[256];
  int i = blockIdx.x * 256 + threadIdx.x;
  int v = (i < N) ? cnt[i] : 0;
  s[threadIdx.x] = v;
  __syncthreads();
#pragma unroll
  for (int off = 1; off < 256; off <<= 1) {
    int t = (threadIdx.x >= off) ? s[threadIdx.x - off] : 0;
    __syncthreads();
    s[threadIdx.x] += t;
    __syncthreads();
  }
  if (i < N) rowptr[i] = s[threadIdx.x] - v;  // exclusive within block
  if (threadIdx.x == 255) bsum[blockIdx.x] = s[255];
}

__global__ __launch_bounds__(512) void scan_bsum_k(int* __restrict__ bsum, int NB) {
  __shared__ int s[512];
  int v = (threadIdx.x < NB) ? bsum[threadIdx.x] : 0;
  s[threadIdx.x] = v;
  __syncthreads();
#pragma unroll
  for (int off = 1; off < 512; off <<= 1) {
    int t = (threadIdx.x >= off) ? s[threadIdx.x - off] : 0;
    __syncthreads();
    s[threadIdx.x] += t;
    __syncthreads();
  }
  if (threadIdx.x < NB) bsum[threadIdx.x] = s[threadIdx.x] - v;  // exclusive block offsets
}

__global__ __launch_bounds__(256) void add_off(int* __restrict__ rowptr,
                                               const int* __restrict__ bsum, int N, int E) {
  int i = blockIdx.x * 256 + threadIdx.x;
  if (i < N) rowptr[i] += bsum[blockIdx.x];
  if (i == 0) rowptr[N] = E;
}

__global__ __launch_bounds__(256) void fill_csr(const int* __restrict__ ei,
                                                const int* __restrict__ rowptr,
                                                int* __restrict__ cursor,
                                                int* __restrict__ colarr, int E) {
  int e = blockIdx.x * 256 + threadIdx.x;
  if (e < E) {
    int d = ei[E + e];
    int pos = rowptr[d] + atomicAdd(&cursor[d], 1);
    colarr[pos] = ei[e];  // src
  }
}

// ---------------- weight convert fp32 -> f16 ----------------

__global__ __launch_bounds__(256) void cvt_w(const float* __restrict__ in,
                                             _Float16* __restrict__ out, int n) {
  int i = blockIdx.x * 256 + threadIdx.x;
  if (i < n) out[i] = (_Float16)in[i];
}

// ---------------- MFMA GEMM: out[N][128] = A[N][K] @ W[128][K]^T ----------------
// A fp32 (CONVA=true, converted in staging) or f16.  W pre-converted f16.
// epilogue: optional per-row scale, optional bias, optional relu; out f16.

template <int K, bool CONVA>
__global__ __launch_bounds__(256) void gemm_mfma(const void* __restrict__ Av,
                                                 const _Float16* __restrict__ Wh,
                                                 const float* __restrict__ bias,
                                                 const float* __restrict__ rowscale,
                                                 _Float16* __restrict__ out,
                                                 int N, int do_relu) {
  // 128x128 tile, BK=64.  LDS tiles f16, XOR-swizzled: byte ^= ((row&7)<<4)
  __shared__ __align__(16) char As[128 * 64 * 2];
  __shared__ __align__(16) char Bs[128 * 64 * 2];

  const int tid = threadIdx.x;
  const int lane = tid & 63;
  const int wave = tid >> 6;
  const int wr = wave >> 1, wc = wave & 1;  // 2x2 wave grid, each 64x64
  const int row0 = blockIdx.x * 128;

  const float* Af = (const float*)Av;
  const _Float16* Ah = (const _Float16*)Av;

  f32x4 acc[4][4] = {};

  for (int k0 = 0; k0 < K; k0 += 64) {
    // stage A: 128 rows x 64 f16 = 1024 chunks of 16B, 4/thread
#pragma unroll
    for (int i = 0; i < 4; ++i) {
      int chunk = tid + i * 256;
      int r = chunk >> 3;
      int q = chunk & 7;
      int gr = row0 + r;
      if (gr >= N) gr = N - 1;  // clamp (safe: stores masked later)
      int byte = (r << 7) | (((q ^ (r & 7)) << 4));
      if (CONVA) {
        const float* src = Af + (size_t)gr * K + k0 + q * 8;
        float4 f0 = *(const float4*)(src);
        float4 f1 = *(const float4*)(src + 4);
        half8 h;
        h[0] = (_Float16)f0.x; h[1] = (_Float16)f0.y;
        h[2] = (_Float16)f0.z; h[3] = (_Float16)f0.w;
        h[4] = (_Float16)f1.x; h[5] = (_Float16)f1.y;
        h[6] = (_Float16)f1.z; h[7] = (_Float16)f1.w;
        *(half8*)(As + byte) = h;
      } else {
        *(half8*)(As + byte) = *(const half8*)(Ah + (size_t)gr * K + k0 + q * 8);
      }
    }
    // stage B: W[c][k0..k0+63], same layout
#pragma unroll
    for (int i = 0; i < 4; ++i) {
      int chunk = tid + i * 256;
      int c = chunk >> 3;
      int q = chunk & 7;
      int byte = (c << 7) | (((q ^ (c & 7)) << 4));
      *(half8*)(Bs + byte) = *(const half8*)(Wh + (size_t)c * K + k0 + q * 8);
    }
    __syncthreads();

#pragma unroll
    for (int ks = 0; ks < 2; ++ks) {
      half8 a[4], b[4];
#pragma unroll
      for (int mi = 0; mi < 4; ++mi) {
        int r = wr * 64 + mi * 16 + (lane & 15);
        int q = ks * 4 + (lane >> 4);
        a[mi] = *(const half8*)(As + ((r << 7) | ((q ^ (r & 7)) << 4)));
      }
#pragma unroll
      for (int ni = 0; ni < 4; ++ni) {
        int c = wc * 64 + ni * 16 + (lane & 15);
        int q = ks * 4 + (lane >> 4);
        b[ni] = *(const half8*)(Bs + ((c << 7) | ((q ^ (c & 7)) << 4)));
      }
#pragma unroll
      for (int mi = 0; mi < 4; ++mi)
#pragma unroll
        for (int ni = 0; ni < 4; ++ni)
          acc[mi][ni] = __builtin_amdgcn_mfma_f32_16x16x32_f16(a[mi], b[ni], acc[mi][ni], 0, 0, 0);
    }
    __syncthreads();
  }

  // epilogue: C/D layout col = lane&15 (+16*ni+64*wc), row = (lane>>4)*4 + j (+16*mi+64*wr)
  const int cbase = wc * 64 + (lane & 15);
  const int rsub = (lane >> 4) * 4;
#pragma unroll
  for (int mi = 0; mi < 4; ++mi) {
#pragma unroll
    for (int j = 0; j < 4; ++j) {
      int gr = row0 + wr * 64 + mi * 16 + rsub + j;
      if (gr < N) {
        float rs = rowscale ? rowscale[gr] : 1.0f;
#pragma unroll
        for (int ni = 0; ni < 4; ++ni) {
          int c = cbase + ni * 16;
          float v = acc[mi][ni][j] * rs;
          if (bias) v += bias[c];
          if (do_relu) v = fmaxf(v, 0.f);
          out[(size_t)gr * HID + c] = (_Float16)v;
        }
      }
    }
  }
}

// ---------------- sparse aggregation (f16 rows, fp32 accumulate) ----------------
// out[i] = relu(dinv[i] * (g[i] + sum_{e in in(i)} g[src_e]) + bias)

__global__ __launch_bounds__(256) void agg_f16(const _Float16* __restrict__ g,
                                               const int* __restrict__ rowptr,
                                               const int* __restrict__ colarr,
                                               const float* __restrict__ dinv,
                                               const float* __restrict__ bias,
                                               _Float16* __restrict__ out, int N) {
  int node = blockIdx.x * 4 + (threadIdx.x >> 6);
  int lane = threadIdx.x & 63;
  if (node >= N) return;
  const int f = lane * 2;

  half2v s = *(const half2v*)(g + (size_t)node * HID + f);
  float ax = (float)s[0], ay = (float)s[1];
  float bx = 0.f, by = 0.f, cx = 0.f, cy = 0.f, dx = 0.f, dy = 0.f;

  int e = rowptr[node];
  const int end = rowptr[node + 1];
  for (; e + 3 < end; e += 4) {
    int c0 = colarr[e], c1 = colarr[e + 1], c2 = colarr[e + 2], c3 = colarr[e + 3];
    half2v v0 = *(const half2v*)(g + (size_t)c0 * HID + f);
    half2v v1 = *(const half2v*)(g + (size_t)c1 * HID + f);
    half2v v2 = *(const half2v*)(g + (size_t)c2 * HID + f);
    half2v v3 = *(const half2v*)(g + (size_t)c3 * HID + f);
    ax += (float)v0[0]; ay += (float)v0[1];
    bx += (float)v1[0]; by += (float)v1[1];
    cx += (float)v2[0]; cy += (float)v2[1];
    dx += (float)v3[0]; dy += (float)v3[1];
  }
  for (; e < end; ++e) {
    int c0 = colarr[e];
    half2v v0 = *(const half2v*)(g + (size_t)c0 * HID + f);
    ax += (float)v0[0]; ay += (float)v0[1];
  }

  float di = dinv[node];
  float vx = di * (ax + bx + cx + dx) + bias[f];
  float vy = di * (ay + by + cy + dy) + bias[f + 1];
  half2v o;
  o[0] = (_Float16)fmaxf(vx, 0.f);
  o[1] = (_Float16)fmaxf(vy, 0.f);
  *(half2v*)(out + (size_t)node * HID + f) = o;
}

// ---------------- final GEMM: logits[N][40] = h[N][128] @ Wl[40][128]^T + bl ----------------

__global__ __launch_bounds__(256) void gemm40(const _Float16* __restrict__ h,
                                              const float* __restrict__ Wl,
                                              const float* __restrict__ bl,
                                              float* __restrict__ out, int N) {
  __shared__ float hs[64][129];
  __shared__ float ws[128][40];
  const int tid = threadIdx.x;
  const int row0 = blockIdx.x * 64;

  for (int idx = tid; idx < 40 * 128; idx += 256) {
    int c = idx >> 7;
    int k = idx & 127;
    ws[k][c] = Wl[idx];  // Wl[c][k]
  }
#pragma unroll
  for (int i = 0; i < 4; ++i) {
    int idx = tid + i * 256;  // 1024 chunks of 8 f16
    int r = idx >> 4;
    int q = idx & 15;
    int gr = row0 + r;
    if (gr >= N) gr = N - 1;
    half8 v = *(const half8*)(h + (size_t)gr * HID + q * 8);
#pragma unroll
    for (int j = 0; j < 8; ++j) hs[r][q * 8 + j] = (float)v[j];
  }
  __syncthreads();

  const int cg = tid & 7;   // 8 col groups of 5 cols
  const int rw = tid >> 3;  // 0..31; rows rw and rw+32
  float acc[2][5] = {};
#pragma unroll 4
  for (int k = 0; k < 128; ++k) {
    float a0 = hs[rw][k];
    float a1 = hs[rw + 32][k];
#pragma unroll
    for (int j = 0; j < 5; ++j) {
      float w = ws[k][cg * 5 + j];
      acc[0][j] += a0 * w;
      acc[1][j] += a1 * w;
    }
  }
#pragma unroll
  for (int half = 0; half < 2; ++half) {
    int gr = row0 + rw + half * 32;
    if (gr < N) {
#pragma unroll
      for (int j = 0; j < 5; ++j) {
        int c = cg * 5 + j;
        out[(size_t)gr * 40 + c] = acc[half][j] + bl[c];
      }
    }
  }
}

// ---------------- launch ----------------

extern "C" void kernel_launch(void* const* d_in, const int* in_sizes, int n_in,
                              void* d_out, int out_size, void* d_ws, size_t ws_size,
                              hipStream_t stream) {
  const float* x = (const float*)d_in[0];
  const int* ei = (const int*)d_in[1];
  const float* W0 = (const float*)d_in[2];
  const float* b0 = (const float*)d_in[3];
  const float* Wc = (const float*)d_in[4];
  const float* bc = (const float*)d_in[5];
  const float* Wl = (const float*)d_in[6];
  const float* bl = (const float*)d_in[7];
  float* out = (float*)d_out;

  const int N = in_sizes[0] / 512;
  const int E = in_sizes[1] / 2;

  char* ws = (char*)d_ws;
  size_t off = 0;
  auto alloc = [&](size_t bytes) -> char* {
    char* p = ws + off;
    off += (bytes + 511) & ~(size_t)511;
    return p;
  };
  float* dinv = (float*)alloc((size_t)N * 4);
  int* cnt = (int*)alloc((size_t)N * 4);
  int* rowptr = (int*)alloc((size_t)(N + 1) * 4);
  int* bsum = (int*)alloc(512 * 4);
  int* colarr = (int*)alloc((size_t)E * 4);
  _Float16* hA = (_Float16*)alloc((size_t)N * HID * 2);
  _Float16* hB = (_Float16*)alloc((size_t)N * HID * 2);
  _Float16* hG = (_Float16*)alloc((size_t)N * HID * 2);
  _Float16* W0h = (_Float16*)alloc((size_t)HID * 512 * 2);
  _Float16* Wch = (_Float16*)alloc((size_t)3 * HID * HID * 2);

  const int nb_n = (N + 255) / 256;
  const int nb_e = (E + 255) / 256;
  const int nb_g = (N + 127) / 128;

  hipMemsetAsync(cnt, 0, (size_t)N * 4, stream);
  count_dst<<<nb_e, 256, 0, stream>>>(ei, cnt, E);
  compute_dinv<<<nb_n, 256, 0, stream>>>(cnt, dinv, N);
  scan_block<<<nb_n, 256, 0, stream>>>(cnt, rowptr, bsum, N);
  scan_bsum_k<<<1, 512, 0, stream>>>(bsum, nb_n);
  add_off<<<nb_n, 256, 0, stream>>>(rowptr, bsum, N, E);
  hipMemsetAsync(cnt, 0, (size_t)N * 4, stream);
  fill_csr<<<nb_e, 256, 0, stream>>>(ei, rowptr, cnt, colarr, E);

  cvt_w<<<(HID * 512 + 255) / 256, 256, 0, stream>>>(W0, W0h, HID * 512);
  cvt_w<<<(3 * HID * HID + 255) / 256, 256, 0, stream>>>(Wc, Wch, 3 * HID * HID);

  // input layer: hA = relu(x @ W0^T + b0)
  gemm_mfma<512, true><<<nb_g, 256, 0, stream>>>(x, W0h, b0, nullptr, hA, N, 1);

  _Float16* bufs[2] = {hA, hB};
  int cur = 0;
  for (int l = 0; l < 3; ++l) {
    // g = dinv * (h @ Wc[l]^T)
    gemm_mfma<128, false><<<nb_g, 256, 0, stream>>>(bufs[cur], Wch + (size_t)l * HID * HID,
                                                    nullptr, dinv, hG, N, 0);
    // h' = relu(dinv * (g[i] + sum g[src]) + bc[l])
    agg_f16<<<(N + 3) / 4, 256, 0, stream>>>(hG, rowptr, colarr, dinv, bc + (size_t)l * HID,
                                             bufs[1 - cur], N);
    cur = 1 - cur;
  }

  gemm40<<<nb_g * 2, 256, 0, stream>>>(bufs[cur], Wl, bl, out, N);
}

// Round 3
// 577.387 us; speedup vs baseline: 2.6960x; 1.0059x over previous
//
#include <hip/hip_runtime.h>

#define HID 128

typedef _Float16 half8 __attribute__((ext_vector_type(8)));
typedef _Float16 half2v __attribute__((ext_vector_type(2)));
typedef float f32x4 __attribute__((ext_vector_type(4)));

// ---------------- CSR build ----------------

__global__ __launch_bounds__(256) void zero_i32(int* __restrict__ p, int n) {
  int i = blockIdx.x * 256 + threadIdx.x;
  if (i < n) p[i] = 0;
}

__global__ __launch_bounds__(256) void count_dst(const int* __restrict__ ei,
                                                 int* __restrict__ cnt, int E) {
  int e = blockIdx.x * 256 + threadIdx.x;
  if (e < E) atomicAdd(&cnt[ei[E + e]], 1);
}

__global__ __launch_bounds__(256) void compute_dinv(const int* __restrict__ cnt,
                                                    float* __restrict__ dinv, int N) {
  int i = blockIdx.x * 256 + threadIdx.x;
  if (i < N) dinv[i] = rsqrtf((float)(cnt[i] + 1));
}

__global__ __launch_bounds__(256) void scan_block(const int* __restrict__ cnt,
                                                  int* __restrict__ rowptr,
                                                  int* __restrict__ bsum, int N) {
  __shared__ int s[256];
  int i = blockIdx.x * 256 + threadIdx.x;
  int v = (i < N) ? cnt[i] : 0;
  s[threadIdx.x] = v;
  __syncthreads();
#pragma unroll
  for (int off = 1; off < 256; off <<= 1) {
    int t = (threadIdx.x >= off) ? s[threadIdx.x - off] : 0;
    __syncthreads();
    s[threadIdx.x] += t;
    __syncthreads();
  }
  if (i < N) rowptr[i] = s[threadIdx.x] - v;  // exclusive within block
  if (threadIdx.x == 255) bsum[blockIdx.x] = s[255];
}

__global__ __launch_bounds__(512) void scan_bsum_k(int* __restrict__ bsum, int NB) {
  __shared__ int s[512];
  int v = (threadIdx.x < NB) ? bsum[threadIdx.x] : 0;
  s[threadIdx.x] = v;
  __syncthreads();
#pragma unroll
  for (int off = 1; off < 512; off <<= 1) {
    int t = (threadIdx.x >= off) ? s[threadIdx.x - off] : 0;
    __syncthreads();
    s[threadIdx.x] += t;
    __syncthreads();
  }
  if (threadIdx.x < NB) bsum[threadIdx.x] = s[threadIdx.x] - v;  // exclusive block offsets
}

__global__ __launch_bounds__(256) void add_off(int* __restrict__ rowptr,
                                               const int* __restrict__ bsum, int N, int E) {
  int i = blockIdx.x * 256 + threadIdx.x;
  if (i < N) rowptr[i] += bsum[blockIdx.x];
  if (i == 0) rowptr[N] = E;
}

// uses cnt (holding indegree) as a down-counting cursor; leaves cnt == 0
__global__ __launch_bounds__(256) void fill_csr(const int* __restrict__ ei,
                                                const int* __restrict__ rowptr,
                                                int* __restrict__ cnt,
                                                int* __restrict__ colarr, int E) {
  int e = blockIdx.x * 256 + threadIdx.x;
  if (e < E) {
    int d = ei[E + e];
    int old = atomicSub(&cnt[d], 1);
    colarr[rowptr[d] + old - 1] = ei[e];  // src
  }
}

// ---------------- weight convert fp32 -> f16 ----------------

__global__ __launch_bounds__(256) void cvt_w(const float* __restrict__ in,
                                             _Float16* __restrict__ out, int n) {
  int i = blockIdx.x * 256 + threadIdx.x;
  if (i < n) out[i] = (_Float16)in[i];
}

// ---------------- MFMA GEMM: out[N][128] = A[N][K] @ W[128][K]^T ----------------
// A fp32 (CONVA=true, converted in staging) or f16.  W pre-converted f16.
// epilogue: optional per-row scale, optional bias, optional relu; out f16.

template <int K, bool CONVA>
__global__ __launch_bounds__(256) void gemm_mfma(const void* __restrict__ Av,
                                                 const _Float16* __restrict__ Wh,
                                                 const float* __restrict__ bias,
                                                 const float* __restrict__ rowscale,
                                                 _Float16* __restrict__ out,
                                                 int N, int do_relu) {
  // 128x128 tile, BK=64.  LDS tiles f16, XOR-swizzled: byte ^= ((row&7)<<4)
  __shared__ __align__(16) char As[128 * 64 * 2];
  __shared__ __align__(16) char Bs[128 * 64 * 2];

  const int tid = threadIdx.x;
  const int lane = tid & 63;
  const int wave = tid >> 6;
  const int wr = wave >> 1, wc = wave & 1;  // 2x2 wave grid, each 64x64
  const int row0 = blockIdx.x * 128;

  const float* Af = (const float*)Av;
  const _Float16* Ah = (const _Float16*)Av;

  f32x4 acc[4][4] = {};

  for (int k0 = 0; k0 < K; k0 += 64) {
    // stage A: 128 rows x 64 f16 = 1024 chunks of 16B, 4/thread
#pragma unroll
    for (int i = 0; i < 4; ++i) {
      int chunk = tid + i * 256;
      int r = chunk >> 3;
      int q = chunk & 7;
      int gr = row0 + r;
      if (gr >= N) gr = N - 1;  // clamp (safe: stores masked later)
      int byte = (r << 7) | (((q ^ (r & 7)) << 4));
      if (CONVA) {
        const float* src = Af + (size_t)gr * K + k0 + q * 8;
        float4 f0 = *(const float4*)(src);
        float4 f1 = *(const float4*)(src + 4);
        half8 h;
        h[0] = (_Float16)f0.x; h[1] = (_Float16)f0.y;
        h[2] = (_Float16)f0.z; h[3] = (_Float16)f0.w;
        h[4] = (_Float16)f1.x; h[5] = (_Float16)f1.y;
        h[6] = (_Float16)f1.z; h[7] = (_Float16)f1.w;
        *(half8*)(As + byte) = h;
      } else {
        *(half8*)(As + byte) = *(const half8*)(Ah + (size_t)gr * K + k0 + q * 8);
      }
    }
    // stage B: W[c][k0..k0+63], same layout
#pragma unroll
    for (int i = 0; i < 4; ++i) {
      int chunk = tid + i * 256;
      int c = chunk >> 3;
      int q = chunk & 7;
      int byte = (c << 7) | (((q ^ (c & 7)) << 4));
      *(half8*)(Bs + byte) = *(const half8*)(Wh + (size_t)c * K + k0 + q * 8);
    }
    __syncthreads();

#pragma unroll
    for (int ks = 0; ks < 2; ++ks) {
      half8 a[4], b[4];
#pragma unroll
      for (int mi = 0; mi < 4; ++mi) {
        int r = wr * 64 + mi * 16 + (lane & 15);
        int q = ks * 4 + (lane >> 4);
        a[mi] = *(const half8*)(As + ((r << 7) | ((q ^ (r & 7)) << 4)));
      }
#pragma unroll
      for (int ni = 0; ni < 4; ++ni) {
        int c = wc * 64 + ni * 16 + (lane & 15);
        int q = ks * 4 + (lane >> 4);
        b[ni] = *(const half8*)(Bs + ((c << 7) | ((q ^ (c & 7)) << 4)));
      }
#pragma unroll
      for (int mi = 0; mi < 4; ++mi)
#pragma unroll
        for (int ni = 0; ni < 4; ++ni)
          acc[mi][ni] = __builtin_amdgcn_mfma_f32_16x16x32_f16(a[mi], b[ni], acc[mi][ni], 0, 0, 0);
    }
    __syncthreads();
  }

  // epilogue: C/D layout col = lane&15 (+16*ni+64*wc), row = (lane>>4)*4 + j (+16*mi+64*wr)
  const int cbase = wc * 64 + (lane & 15);
  const int rsub = (lane >> 4) * 4;
#pragma unroll
  for (int mi = 0; mi < 4; ++mi) {
#pragma unroll
    for (int j = 0; j < 4; ++j) {
      int gr = row0 + wr * 64 + mi * 16 + rsub + j;
      if (gr < N) {
        float rs = rowscale ? rowscale[gr] : 1.0f;
#pragma unroll
        for (int ni = 0; ni < 4; ++ni) {
          int c = cbase + ni * 16;
          float v = acc[mi][ni][j] * rs;
          if (bias) v += bias[c];
          if (do_relu) v = fmaxf(v, 0.f);
          out[(size_t)gr * HID + c] = (_Float16)v;
        }
      }
    }
  }
}

// ---------------- sparse aggregation (f16 rows, fp32 accumulate) ----------------
// out[i] = relu(dinv[i] * (g[i] + sum_{e in in(i)} g[src_e]) + bias)

__global__ __launch_bounds__(256) void agg_f16(const _Float16* __restrict__ g,
                                               const int* __restrict__ rowptr,
                                               const int* __restrict__ colarr,
                                               const float* __restrict__ dinv,
                                               const float* __restrict__ bias,
                                               _Float16* __restrict__ out, int N) {
  int node = blockIdx.x * 4 + (threadIdx.x >> 6);
  int lane = threadIdx.x & 63;
  if (node >= N) return;
  const int f = lane * 2;

  half2v s = *(const half2v*)(g + (size_t)node * HID + f);
  float ax = (float)s[0], ay = (float)s[1];
  float bx = 0.f, by = 0.f, cx = 0.f, cy = 0.f, dx = 0.f, dy = 0.f;

  int e = rowptr[node];
  const int end = rowptr[node + 1];
  for (; e + 3 < end; e += 4) {
    int c0 = colarr[e], c1 = colarr[e + 1], c2 = colarr[e + 2], c3 = colarr[e + 3];
    half2v v0 = *(const half2v*)(g + (size_t)c0 * HID + f);
    half2v v1 = *(const half2v*)(g + (size_t)c1 * HID + f);
    half2v v2 = *(const half2v*)(g + (size_t)c2 * HID + f);
    half2v v3 = *(const half2v*)(g + (size_t)c3 * HID + f);
    ax += (float)v0[0]; ay += (float)v0[1];
    bx += (float)v1[0]; by += (float)v1[1];
    cx += (float)v2[0]; cy += (float)v2[1];
    dx += (float)v3[0]; dy += (float)v3[1];
  }
  for (; e < end; ++e) {
    int c0 = colarr[e];
    half2v v0 = *(const half2v*)(g + (size_t)c0 * HID + f);
    ax += (float)v0[0]; ay += (float)v0[1];
  }

  float di = dinv[node];
  float vx = di * (ax + bx + cx + dx) + bias[f];
  float vy = di * (ay + by + cy + dy) + bias[f + 1];
  half2v o;
  o[0] = (_Float16)fmaxf(vx, 0.f);
  o[1] = (_Float16)fmaxf(vy, 0.f);
  *(half2v*)(out + (size_t)node * HID + f) = o;
}

// ---------------- final GEMM: logits[N][40] = h[N][128] @ Wl[40][128]^T + bl ----------------

__global__ __launch_bounds__(256) void gemm40(const _Float16* __restrict__ h,
                                              const float* __restrict__ Wl,
                                              const float* __restrict__ bl,
                                              float* __restrict__ out, int N) {
  __shared__ float hs[64][129];
  __shared__ float ws[128][40];
  const int tid = threadIdx.x;
  const int row0 = blockIdx.x * 64;

  for (int idx = tid; idx < 40 * 128; idx += 256) {
    int c = idx >> 7;
    int k = idx & 127;
    ws[k][c] = Wl[idx];  // Wl[c][k]
  }
#pragma unroll
  for (int i = 0; i < 4; ++i) {
    int idx = tid + i * 256;  // 1024 chunks of 8 f16
    int r = idx >> 4;
    int q = idx & 15;
    int gr = row0 + r;
    if (gr >= N) gr = N - 1;
    half8 v = *(const half8*)(h + (size_t)gr * HID + q * 8);
#pragma unroll
    for (int j = 0; j < 8; ++j) hs[r][q * 8 + j] = (float)v[j];
  }
  __syncthreads();

  const int cg = tid & 7;   // 8 col groups of 5 cols
  const int rw = tid >> 3;  // 0..31; rows rw and rw+32
  float acc[2][5] = {};
#pragma unroll 4
  for (int k = 0; k < 128; ++k) {
    float a0 = hs[rw][k];
    float a1 = hs[rw + 32][k];
#pragma unroll
    for (int j = 0; j < 5; ++j) {
      float w = ws[k][cg * 5 + j];
      acc[0][j] += a0 * w;
      acc[1][j] += a1 * w;
    }
  }
#pragma unroll
  for (int half = 0; half < 2; ++half) {
    int gr = row0 + rw + half * 32;
    if (gr < N) {
#pragma unroll
      for (int j = 0; j < 5; ++j) {
        int c = cg * 5 + j;
        out[(size_t)gr * 40 + c] = acc[half][j] + bl[c];
      }
    }
  }
}

// ---------------- launch ----------------

extern "C" void kernel_launch(void* const* d_in, const int* in_sizes, int n_in,
                              void* d_out, int out_size, void* d_ws, size_t ws_size,
                              hipStream_t stream) {
  const float* x = (const float*)d_in[0];
  const int* ei = (const int*)d_in[1];
  const float* W0 = (const float*)d_in[2];
  const float* b0 = (const float*)d_in[3];
  const float* Wc = (const float*)d_in[4];
  const float* bc = (const float*)d_in[5];
  const float* Wl = (const float*)d_in[6];
  const float* bl = (const float*)d_in[7];
  float* out = (float*)d_out;

  const int N = in_sizes[0] / 512;
  const int E = in_sizes[1] / 2;

  char* ws = (char*)d_ws;
  size_t off = 0;
  auto alloc = [&](size_t bytes) -> char* {
    char* p = ws + off;
    off += (bytes + 511) & ~(size_t)511;
    return p;
  };
  float* dinv = (float*)alloc((size_t)N * 4);
  int* cnt = (int*)alloc((size_t)N * 4);
  int* rowptr = (int*)alloc((size_t)(N + 1) * 4);
  int* bsum = (int*)alloc(512 * 4);
  int* colarr = (int*)alloc((size_t)E * 4);
  _Float16* hA = (_Float16*)alloc((size_t)N * HID * 2);
  _Float16* hB = (_Float16*)alloc((size_t)N * HID * 2);
  _Float16* hG = (_Float16*)alloc((size_t)N * HID * 2);
  _Float16* W0h = (_Float16*)alloc((size_t)HID * 512 * 2);
  _Float16* Wch = (_Float16*)alloc((size_t)3 * HID * HID * 2);

  const int nb_n = (N + 255) / 256;
  const int nb_e = (E + 255) / 256;
  const int nb_g = (N + 127) / 128;

  zero_i32<<<nb_n, 256, 0, stream>>>(cnt, N);
  count_dst<<<nb_e, 256, 0, stream>>>(ei, cnt, E);
  compute_dinv<<<nb_n, 256, 0, stream>>>(cnt, dinv, N);
  scan_block<<<nb_n, 256, 0, stream>>>(cnt, rowptr, bsum, N);
  scan_bsum_k<<<1, 512, 0, stream>>>(bsum, nb_n);
  add_off<<<nb_n, 256, 0, stream>>>(rowptr, bsum, N, E);
  fill_csr<<<nb_e, 256, 0, stream>>>(ei, rowptr, cnt, colarr, E);

  cvt_w<<<(HID * 512 + 255) / 256, 256, 0, stream>>>(W0, W0h, HID * 512);
  cvt_w<<<(3 * HID * HID + 255) / 256, 256, 0, stream>>>(Wc, Wch, 3 * HID * HID);

  // input layer: hA = relu(x @ W0^T + b0)
  gemm_mfma<512, true><<<nb_g, 256, 0, stream>>>(x, W0h, b0, nullptr, hA, N, 1);

  _Float16* bufs[2] = {hA, hB};
  int cur = 0;
  for (int l = 0; l < 3; ++l) {
    // g = dinv * (h @ Wc[l]^T)
    gemm_mfma<128, false><<<nb_g, 256, 0, stream>>>(bufs[cur], Wch + (size_t)l * HID * HID,
                                                    nullptr, dinv, hG, N, 0);
    // h' = relu(dinv * (g[i] + sum g[src]) + bc[l])
    agg_f16<<<(N + 3) / 4, 256, 0, stream>>>(hG, rowptr, colarr, dinv, bc + (size_t)l * HID,
                                             bufs[1 - cur], N);
    cur = 1 - cur;
  }

  gemm40<<<nb_g * 2, 256, 0, stream>>>(bufs[cur], Wl, bl, out, N);
}

// Round 4
// 491.095 us; speedup vs baseline: 3.1698x; 1.1757x over previous
//
#include <hip/hip_runtime.h>

#define HID 128

typedef _Float16 half8 __attribute__((ext_vector_type(8)));
typedef _Float16 half4v __attribute__((ext_vector_type(4)));
typedef _Float16 half2v __attribute__((ext_vector_type(2)));
typedef float f32x4 __attribute__((ext_vector_type(4)));

// ---------------- CSR build ----------------

__global__ __launch_bounds__(256) void zero_i32(int* __restrict__ p, int n) {
  int i = blockIdx.x * 256 + threadIdx.x;
  if (i < n) p[i] = 0;
}

__global__ __launch_bounds__(256) void count_dst(const int* __restrict__ ei,
                                                 int* __restrict__ cnt, int E) {
  int e = blockIdx.x * 256 + threadIdx.x;
  if (e < E) atomicAdd(&cnt[ei[E + e]], 1);
}

// also emits dinv = rsqrt(cnt+1)
__global__ __launch_bounds__(256) void scan_block(const int* __restrict__ cnt,
                                                  int* __restrict__ rowptr,
                                                  int* __restrict__ bsum,
                                                  float* __restrict__ dinv, int N) {
  __shared__ int s[256];
  int i = blockIdx.x * 256 + threadIdx.x;
  int v = (i < N) ? cnt[i] : 0;
  if (i < N) dinv[i] = rsqrtf((float)(v + 1));
  s[threadIdx.x] = v;
  __syncthreads();
#pragma unroll
  for (int off = 1; off < 256; off <<= 1) {
    int t = (threadIdx.x >= off) ? s[threadIdx.x - off] : 0;
    __syncthreads();
    s[threadIdx.x] += t;
    __syncthreads();
  }
  if (i < N) rowptr[i] = s[threadIdx.x] - v;  // exclusive within block
  if (threadIdx.x == 255) bsum[blockIdx.x] = s[255];
}

__global__ __launch_bounds__(512) void scan_bsum_k(int* __restrict__ bsum, int NB) {
  __shared__ int s[512];
  int v = (threadIdx.x < NB) ? bsum[threadIdx.x] : 0;
  s[threadIdx.x] = v;
  __syncthreads();
#pragma unroll
  for (int off = 1; off < 512; off <<= 1) {
    int t = (threadIdx.x >= off) ? s[threadIdx.x - off] : 0;
    __syncthreads();
    s[threadIdx.x] += t;
    __syncthreads();
  }
  if (threadIdx.x < NB) bsum[threadIdx.x] = s[threadIdx.x] - v;  // exclusive block offsets
}

__global__ __launch_bounds__(256) void add_off(int* __restrict__ rowptr,
                                               const int* __restrict__ bsum, int N, int E) {
  int i = blockIdx.x * 256 + threadIdx.x;
  if (i < N) rowptr[i] += bsum[blockIdx.x];
  if (i == 0) rowptr[N] = E;
}

// uses cnt (holding indegree) as a down-counting cursor; leaves cnt == 0
__global__ __launch_bounds__(256) void fill_csr(const int* __restrict__ ei,
                                                const int* __restrict__ rowptr,
                                                int* __restrict__ cnt,
                                                int* __restrict__ colarr, int E) {
  int e = blockIdx.x * 256 + threadIdx.x;
  if (e < E) {
    int d = ei[E + e];
    int old = atomicSub(&cnt[d], 1);
    colarr[rowptr[d] + old - 1] = ei[e];  // src
  }
}

// ---------------- weight convert fp32 -> f16 (both weight tensors, one launch) ----------------

__global__ __launch_bounds__(256) void cvt_w2(const float* __restrict__ a, int na,
                                              const float* __restrict__ b, int nb,
                                              _Float16* __restrict__ oa,
                                              _Float16* __restrict__ ob) {
  int i = blockIdx.x * 256 + threadIdx.x;
  if (i < na) oa[i] = (_Float16)a[i];
  else if (i < na + nb) ob[i - na] = (_Float16)b[i - na];
}

// ---------------- MFMA GEMM: out[N][128] = A[N][K] @ W[128][K]^T ----------------

template <int K, bool CONVA>
__global__ __launch_bounds__(256) void gemm_mfma(const void* __restrict__ Av,
                                                 const _Float16* __restrict__ Wh,
                                                 const float* __restrict__ bias,
                                                 const float* __restrict__ rowscale,
                                                 _Float16* __restrict__ out,
                                                 int N, int do_relu) {
  // 128x128 tile, BK=64.  LDS tiles f16, XOR-swizzled: byte ^= ((row&7)<<4)
  __shared__ __align__(16) char As[128 * 64 * 2];
  __shared__ __align__(16) char Bs[128 * 64 * 2];

  const int tid = threadIdx.x;
  const int lane = tid & 63;
  const int wave = tid >> 6;
  const int wr = wave >> 1, wc = wave & 1;  // 2x2 wave grid, each 64x64
  const int row0 = blockIdx.x * 128;

  const float* Af = (const float*)Av;
  const _Float16* Ah = (const _Float16*)Av;

  f32x4 acc[4][4] = {};

  for (int k0 = 0; k0 < K; k0 += 64) {
    // stage A: 128 rows x 64 f16 = 1024 chunks of 16B, 4/thread
#pragma unroll
    for (int i = 0; i < 4; ++i) {
      int chunk = tid + i * 256;
      int r = chunk >> 3;
      int q = chunk & 7;
      int gr = row0 + r;
      if (gr >= N) gr = N - 1;  // clamp (safe: stores masked later)
      int byte = (r << 7) | (((q ^ (r & 7)) << 4));
      if (CONVA) {
        const float* src = Af + (size_t)gr * K + k0 + q * 8;
        float4 f0 = *(const float4*)(src);
        float4 f1 = *(const float4*)(src + 4);
        half8 h;
        h[0] = (_Float16)f0.x; h[1] = (_Float16)f0.y;
        h[2] = (_Float16)f0.z; h[3] = (_Float16)f0.w;
        h[4] = (_Float16)f1.x; h[5] = (_Float16)f1.y;
        h[6] = (_Float16)f1.z; h[7] = (_Float16)f1.w;
        *(half8*)(As + byte) = h;
      } else {
        *(half8*)(As + byte) = *(const half8*)(Ah + (size_t)gr * K + k0 + q * 8);
      }
    }
    // stage B: W[c][k0..k0+63], same layout
#pragma unroll
    for (int i = 0; i < 4; ++i) {
      int chunk = tid + i * 256;
      int c = chunk >> 3;
      int q = chunk & 7;
      int byte = (c << 7) | (((q ^ (c & 7)) << 4));
      *(half8*)(Bs + byte) = *(const half8*)(Wh + (size_t)c * K + k0 + q * 8);
    }
    __syncthreads();

#pragma unroll
    for (int ks = 0; ks < 2; ++ks) {
      half8 a[4], b[4];
#pragma unroll
      for (int mi = 0; mi < 4; ++mi) {
        int r = wr * 64 + mi * 16 + (lane & 15);
        int q = ks * 4 + (lane >> 4);
        a[mi] = *(const half8*)(As + ((r << 7) | ((q ^ (r & 7)) << 4)));
      }
#pragma unroll
      for (int ni = 0; ni < 4; ++ni) {
        int c = wc * 64 + ni * 16 + (lane & 15);
        int q = ks * 4 + (lane >> 4);
        b[ni] = *(const half8*)(Bs + ((c << 7) | ((q ^ (c & 7)) << 4)));
      }
#pragma unroll
      for (int mi = 0; mi < 4; ++mi)
#pragma unroll
        for (int ni = 0; ni < 4; ++ni)
          acc[mi][ni] = __builtin_amdgcn_mfma_f32_16x16x32_f16(a[mi], b[ni], acc[mi][ni], 0, 0, 0);
    }
    __syncthreads();
  }

  // epilogue: col = lane&15 (+16*ni+64*wc), row = (lane>>4)*4 + j (+16*mi+64*wr)
  const int cbase = wc * 64 + (lane & 15);
  const int rsub = (lane >> 4) * 4;
#pragma unroll
  for (int mi = 0; mi < 4; ++mi) {
#pragma unroll
    for (int j = 0; j < 4; ++j) {
      int gr = row0 + wr * 64 + mi * 16 + rsub + j;
      if (gr < N) {
        float rs = rowscale ? rowscale[gr] : 1.0f;
#pragma unroll
        for (int ni = 0; ni < 4; ++ni) {
          int c = cbase + ni * 16;
          float v = acc[mi][ni][j] * rs;
          if (bias) v += bias[c];
          if (do_relu) v = fmaxf(v, 0.f);
          out[(size_t)gr * HID + c] = (_Float16)v;
        }
      }
    }
  }
}

// ---------------- sparse aggregation (f16 rows, fp32 accumulate) ----------------
// out[i] = relu(dinv[i] * (g[i] + sum_{e in in(i)} g[src_e]) + bias)

__global__ __launch_bounds__(256) void agg_f16(const _Float16* __restrict__ g,
                                               const int* __restrict__ rowptr,
                                               const int* __restrict__ colarr,
                                               const float* __restrict__ dinv,
                                               const float* __restrict__ bias,
                                               _Float16* __restrict__ out, int N) {
  int node = blockIdx.x * 4 + (threadIdx.x >> 6);
  int lane = threadIdx.x & 63;
  if (node >= N) return;
  const int f = lane * 2;

  half2v s = *(const half2v*)(g + (size_t)node * HID + f);
  float a0x = (float)s[0], a0y = (float)s[1];
  float a1x = 0.f, a1y = 0.f, a2x = 0.f, a2y = 0.f, a3x = 0.f, a3y = 0.f;

  int e = rowptr[node];
  const int end = rowptr[node + 1];
  // 8-deep unroll: 8 independent gathers in flight per iteration
  for (; e + 7 < end; e += 8) {
    int c0 = colarr[e],     c1 = colarr[e + 1], c2 = colarr[e + 2], c3 = colarr[e + 3];
    int c4 = colarr[e + 4], c5 = colarr[e + 5], c6 = colarr[e + 6], c7 = colarr[e + 7];
    half2v v0 = *(const half2v*)(g + (size_t)c0 * HID + f);
    half2v v1 = *(const half2v*)(g + (size_t)c1 * HID + f);
    half2v v2 = *(const half2v*)(g + (size_t)c2 * HID + f);
    half2v v3 = *(const half2v*)(g + (size_t)c3 * HID + f);
    half2v v4 = *(const half2v*)(g + (size_t)c4 * HID + f);
    half2v v5 = *(const half2v*)(g + (size_t)c5 * HID + f);
    half2v v6 = *(const half2v*)(g + (size_t)c6 * HID + f);
    half2v v7 = *(const half2v*)(g + (size_t)c7 * HID + f);
    a0x += (float)v0[0] + (float)v4[0]; a0y += (float)v0[1] + (float)v4[1];
    a1x += (float)v1[0] + (float)v5[0]; a1y += (float)v1[1] + (float)v5[1];
    a2x += (float)v2[0] + (float)v6[0]; a2y += (float)v2[1] + (float)v6[1];
    a3x += (float)v3[0] + (float)v7[0]; a3y += (float)v3[1] + (float)v7[1];
  }
  for (; e + 1 < end; e += 2) {
    int c0 = colarr[e], c1 = colarr[e + 1];
    half2v v0 = *(const half2v*)(g + (size_t)c0 * HID + f);
    half2v v1 = *(const half2v*)(g + (size_t)c1 * HID + f);
    a0x += (float)v0[0]; a0y += (float)v0[1];
    a1x += (float)v1[0]; a1y += (float)v1[1];
  }
  if (e < end) {
    half2v v0 = *(const half2v*)(g + (size_t)colarr[e] * HID + f);
    a0x += (float)v0[0]; a0y += (float)v0[1];
  }

  float di = dinv[node];
  float vx = di * (a0x + a1x + a2x + a3x) + bias[f];
  float vy = di * (a0y + a1y + a2y + a3y) + bias[f + 1];
  half2v o;
  o[0] = (_Float16)fmaxf(vx, 0.f);
  o[1] = (_Float16)fmaxf(vy, 0.f);
  *(half2v*)(out + (size_t)node * HID + f) = o;
}

// ---------------- final GEMM (MFMA): logits[N][40] = h[N][128] @ Wl[40][128]^T + bl ----------------
// 128 rows/block (4 waves x 32 rows), 3 col-tiles of 16 (cols 40..47 masked).
// A fragments straight from global (64B-coalesced per row); Wl->f16 in LDS.

__global__ __launch_bounds__(256) void gemm40_mfma(const _Float16* __restrict__ h,
                                                   const float* __restrict__ Wl,
                                                   const float* __restrict__ bl,
                                                   float* __restrict__ out, int N) {
  __shared__ __align__(16) _Float16 wlds[48][136];  // stride 272B: 16B-aligned rows, 2-way-max banks

  const int tid = threadIdx.x;
  const int lane = tid & 63;
  const int wave = tid >> 6;
  const int row0 = blockIdx.x * 128;

  // stage Wl (40x128 fp32) -> wlds (48x128 f16, zero-padded rows 40..47)
#pragma unroll
  for (int i = 0; i < 6; ++i) {
    int idx4 = tid + i * 256;        // 1536 float4 covers 48x128
    int c = idx4 >> 5;               // row 0..47
    int ko = (idx4 & 31) * 4;        // k offset
    float4 v = make_float4(0.f, 0.f, 0.f, 0.f);
    if (c < 40) v = *(const float4*)(Wl + (size_t)c * HID + ko);
    half4v hv;
    hv[0] = (_Float16)v.x; hv[1] = (_Float16)v.y;
    hv[2] = (_Float16)v.z; hv[3] = (_Float16)v.w;
    *(half4v*)&wlds[c][ko] = hv;
  }
  __syncthreads();

  f32x4 acc[2][3] = {};
  const int arow_in = lane & 15;     // A/B fragment row-within-tile
  const int kq = lane >> 4;          // k-quarter

#pragma unroll
  for (int ks = 0; ks < 4; ++ks) {
    half8 a[2], b[3];
#pragma unroll
    for (int mi = 0; mi < 2; ++mi) {
      int gr = row0 + wave * 32 + mi * 16 + arow_in;
      if (gr >= N) gr = N - 1;
      a[mi] = *(const half8*)(h + (size_t)gr * HID + ks * 32 + kq * 8);
    }
#pragma unroll
    for (int ni = 0; ni < 3; ++ni) {
      int c = ni * 16 + arow_in;
      b[ni] = *(const half8*)&wlds[c][ks * 32 + kq * 8];
    }
#pragma unroll
    for (int mi = 0; mi < 2; ++mi)
#pragma unroll
      for (int ni = 0; ni < 3; ++ni)
        acc[mi][ni] = __builtin_amdgcn_mfma_f32_16x16x32_f16(a[mi], b[ni], acc[mi][ni], 0, 0, 0);
  }

  // store: row = row0 + wave*32 + mi*16 + (lane>>4)*4 + j, col = ni*16 + (lane&15)
  const int rsub = (lane >> 4) * 4;
#pragma unroll
  for (int ni = 0; ni < 3; ++ni) {
    int col = ni * 16 + (lane & 15);
    if (col >= 40) continue;
    float bv = bl[col];
#pragma unroll
    for (int mi = 0; mi < 2; ++mi) {
#pragma unroll
      for (int j = 0; j < 4; ++j) {
        int gr = row0 + wave * 32 + mi * 16 + rsub + j;
        if (gr < N) out[(size_t)gr * 40 + col] = acc[mi][ni][j] + bv;
      }
    }
  }
}

// ---------------- launch ----------------

extern "C" void kernel_launch(void* const* d_in, const int* in_sizes, int n_in,
                              void* d_out, int out_size, void* d_ws, size_t ws_size,
                              hipStream_t stream) {
  const float* x = (const float*)d_in[0];
  const int* ei = (const int*)d_in[1];
  const float* W0 = (const float*)d_in[2];
  const float* b0 = (const float*)d_in[3];
  const float* Wc = (const float*)d_in[4];
  const float* bc = (const float*)d_in[5];
  const float* Wl = (const float*)d_in[6];
  const float* bl = (const float*)d_in[7];
  float* out = (float*)d_out;

  const int N = in_sizes[0] / 512;
  const int E = in_sizes[1] / 2;

  char* ws = (char*)d_ws;
  size_t off = 0;
  auto alloc = [&](size_t bytes) -> char* {
    char* p = ws + off;
    off += (bytes + 511) & ~(size_t)511;
    return p;
  };
  float* dinv = (float*)alloc((size_t)N * 4);
  int* cnt = (int*)alloc((size_t)N * 4);
  int* rowptr = (int*)alloc((size_t)(N + 1) * 4);
  int* bsum = (int*)alloc(512 * 4);
  int* colarr = (int*)alloc((size_t)E * 4);
  _Float16* hA = (_Float16*)alloc((size_t)N * HID * 2);
  _Float16* hB = (_Float16*)alloc((size_t)N * HID * 2);
  _Float16* hG = (_Float16*)alloc((size_t)N * HID * 2);
  _Float16* W0h = (_Float16*)alloc((size_t)HID * 512 * 2);
  _Float16* Wch = (_Float16*)alloc((size_t)3 * HID * HID * 2);

  const int nb_n = (N + 255) / 256;
  const int nb_e = (E + 255) / 256;
  const int nb_g = (N + 127) / 128;

  zero_i32<<<nb_n, 256, 0, stream>>>(cnt, N);
  count_dst<<<nb_e, 256, 0, stream>>>(ei, cnt, E);
  scan_block<<<nb_n, 256, 0, stream>>>(cnt, rowptr, bsum, dinv, N);
  scan_bsum_k<<<1, 512, 0, stream>>>(bsum, nb_n);
  add_off<<<nb_n, 256, 0, stream>>>(rowptr, bsum, N, E);
  fill_csr<<<nb_e, 256, 0, stream>>>(ei, rowptr, cnt, colarr, E);

  const int nw0 = HID * 512, nwc = 3 * HID * HID;
  cvt_w2<<<(nw0 + nwc + 255) / 256, 256, 0, stream>>>(W0, nw0, Wc, nwc, W0h, Wch);

  // input layer: hA = relu(x @ W0^T + b0)
  gemm_mfma<512, true><<<nb_g, 256, 0, stream>>>(x, W0h, b0, nullptr, hA, N, 1);

  _Float16* bufs[2] = {hA, hB};
  int cur = 0;
  for (int l = 0; l < 3; ++l) {
    // g = dinv * (h @ Wc[l]^T)
    gemm_mfma<128, false><<<nb_g, 256, 0, stream>>>(bufs[cur], Wch + (size_t)l * HID * HID,
                                                    nullptr, dinv, hG, N, 0);
    // h' = relu(dinv * (g[i] + sum g[src]) + bc[l])
    agg_f16<<<(N + 3) / 4, 256, 0, stream>>>(hG, rowptr, colarr, dinv, bc + (size_t)l * HID,
                                             bufs[1 - cur], N);
    cur = 1 - cur;
  }

  gemm40_mfma<<<nb_g, 256, 0, stream>>>(bufs[cur], Wl, bl, out, N);
}